// Round 9
// baseline (930.748 us; speedup 1.0000x reference)
//
#include <hip/hip_runtime.h>

// ---------------- bf16 helpers (raw ushort storage) ----------------
__device__ __forceinline__ float b2f(unsigned short u) {
    union { unsigned int i; float f; } x; x.i = ((unsigned int)u) << 16; return x.f;
}
__device__ __forceinline__ unsigned short f2b(float f) {
    union { float f; unsigned int i; } x; x.f = f;
    unsigned int r = x.i + 0x7fffu + ((x.i >> 16) & 1u);   // RNE
    return (unsigned short)(r >> 16);
}
__device__ __forceinline__ bool finitef(float x) {
    union { float f; unsigned int u; } c; c.f = x;
    return ((c.u >> 23) & 0xffu) != 0xffu;
}

typedef __attribute__((ext_vector_type(8))) __bf16 bf16x8;
typedef __attribute__((ext_vector_type(4))) float f32x4;

#define HDIM 128
#define LSTR 136

// ---------------- failure-path fill ----------------
__global__ void fill_f32(float* p, int n, float v) {
    int i = blockIdx.x * 256 + threadIdx.x;
    if (i < n) p[i] = v;
}

// ---------------- prep: detect dtype + normalize/transpose W1,W2 + zero cnt/stats/ticket ----------------
__global__ void prep(const unsigned short* __restrict__ X0,
                     const unsigned short* __restrict__ W1, const unsigned short* __restrict__ W2,
                     unsigned short* __restrict__ Wt1, unsigned short* __restrict__ Wt2,
                     int* __restrict__ zbase, int zcount, int* __restrict__ flags) {
    int bid = blockIdx.x, tid = threadIdx.x;
    if (bid < 128) {
        __shared__ int sane;
        if (tid == 0) sane = 0;
        __syncthreads();
        unsigned short u = X0[2 * tid];
        int e = (u >> 7) & 0xff;
        if (e >= 100 && e <= 140) atomicAdd(&sane, 1);
        __syncthreads();
        int isbf = (sane >= 128) ? 1 : 0;
        if (bid == 0 && tid == 0) flags[0] = isbf;
        int idx = bid * 256 + tid;          // 0..32767
        const unsigned short* src; unsigned short* dst; int l;
        if (idx < 16384) { src = W1; dst = Wt1; l = idx; }
        else             { src = W2; dst = Wt2; l = idx - 16384; }
        int k = l >> 7, c = l & 127;
        unsigned short v = isbf ? src[l] : f2b(((const float*)src)[l]);
        dst[c * 128 + k] = v;               // Wt[n][k]
    } else {
        int i = (bid - 128) * 256 + tid;
        if (i < zcount) zbase[i] = 0;
    }
}

// ---------------- edges: dtype detect, compact, clamp, fused degree histogram ----------------
__global__ void edges_norm(const int* __restrict__ ei, int* __restrict__ s32,
                           int* __restrict__ d32, int* __restrict__ cnt, int E, int N) {
    __shared__ int sh;
    if (threadIdx.x == 0) {
        int acc = 0;
        for (int k = 1; k < 129; k += 2) acc |= ei[k];
        sh = (acc == 0) ? 1 : 0;
    }
    __syncthreads();
    int is64 = sh;
    int e = blockIdx.x * 256 + threadIdx.x;
    if (e < E) {
        int s, d;
        if (is64) { s = ei[2 * (size_t)e]; d = ei[2 * (size_t)E + 2 * (size_t)e]; }
        else      { s = ei[e];             d = ei[(size_t)E + e]; }
        s = s < 0 ? 0 : (s >= N ? N - 1 : s);
        d = d < 0 ? 0 : (d >= N ? N - 1 : d);
        s32[e] = s; d32[e] = d;
        atomicAdd(&cnt[d], 1);
    }
}

// ---------------- scan1: per-block sums + dinv ----------------
__global__ void scan1(const int* __restrict__ cnt, int* __restrict__ bsum,
                      float* __restrict__ dinv, int n) {
    __shared__ int sh[256];
    int t = threadIdx.x;
    int i = blockIdx.x * 256 + t;
    int v = (i < n) ? cnt[i] : 0;
    sh[t] = v;
    if (i < n) dinv[i] = rsqrtf((float)v + 1.0f);
    __syncthreads();
    for (int s = 128; s > 0; s >>= 1) {
        if (t < s) sh[t] += sh[t + s];
        __syncthreads();
    }
    if (t == 0) bsum[blockIdx.x] = sh[0];
}

// ---------------- scan3: in-block bsum prefix (scan2 folded) + meta + cursor ----------------
__global__ void scan3(const int* __restrict__ cnt, const int* __restrict__ bsum,
                      int4* __restrict__ meta, int* __restrict__ cursor, int n, int nblk) {
    __shared__ int sb[256];
    __shared__ int sh[256];
    int t = threadIdx.x;
    sb[t] = (t < nblk) ? bsum[t] : 0;
    __syncthreads();
    for (int off = 1; off < 256; off <<= 1) {
        int v = (t >= off) ? sb[t - off] : 0;
        __syncthreads();
        sb[t] += v;
        __syncthreads();
    }
    int bpre = (blockIdx.x == 0) ? 0 : sb[blockIdx.x - 1];

    int i = blockIdx.x * 256 + t;
    int v = (i < n) ? cnt[i] : 0;
    sh[t] = v;
    __syncthreads();
    for (int off = 1; off < 256; off <<= 1) {
        int a = (t >= off) ? sh[t - off] : 0;
        __syncthreads();
        sh[t] += a;
        __syncthreads();
    }
    if (i < n) {
        int excl = sh[t] - v + bpre;
        float dv = rsqrtf((float)v + 1.0f);
        meta[i] = make_int4(excl, v, __float_as_int(dv), 0);
        cursor[i] = excl;
    }
}

__global__ void scatter_k(const int* __restrict__ s32, const int* __restrict__ d32,
                          int* __restrict__ cursor, int* __restrict__ csr, int E) {
    int e = blockIdx.x * 256 + threadIdx.x;
    if (e < E) {
        int slot = atomicAdd(&cursor[d32[e]], 1);
        csr[slot] = s32[e];
    }
}

// ---------------- GEMM (MFMA): Hb[slice][n][32] = dinv[n] * (A[n,128] @ W), slice-major out ----------------
__global__ __launch_bounds__(256) void gemm_mfma(
    const unsigned short* __restrict__ A, const unsigned short* __restrict__ Wt,
    unsigned short* __restrict__ C, const int* __restrict__ aflag, int mode,
    const float* __restrict__ scale, const float* __restrict__ shift,
    const float* __restrict__ dinv, int n, int sstride) {
    __shared__ __align__(16) unsigned short Wl[128 * LSTR];
    __shared__ __align__(16) unsigned short Al[64 * LSTR];
    int tid = threadIdx.x;
    int row0 = blockIdx.x * 64;

    const uint4* Wg = (const uint4*)Wt;
#pragma unroll
    for (int it = 0; it < 8; ++it) {
        int idx = tid + it * 256;
        int nn = idx >> 4, k8 = idx & 15;
        *(uint4*)&Wl[nn * LSTR + k8 * 8] = Wg[idx];
    }

    int amode = (mode == 2) ? 2 : aflag[0];
    if (amode == 1) {
        const uint4* Ag = (const uint4*)A;
        for (int it = 0; it < 4; ++it) {
            int idx = tid + it * 256;
            int r = idx >> 4, cc = idx & 15;
            int gr = row0 + r;
            uint4 v; v.x = v.y = v.z = v.w = 0u;
            if (gr < n) v = Ag[(size_t)gr * 16 + cc];
            *(uint4*)&Al[r * LSTR + cc * 8] = v;
        }
    } else if (amode == 0) {
        const uint4* Af = (const uint4*)A;
        for (int it = 0; it < 8; ++it) {
            int idx = tid + it * 256;
            int r = idx >> 5, c4 = idx & 31;
            int gr = row0 + r;
            uint4 v; v.x = v.y = v.z = v.w = 0u;
            if (gr < n) v = Af[(size_t)gr * 32 + c4];
            float ff[4]; *(uint4*)ff = v;
            ushort4 o;
            o.x = f2b(ff[0]); o.y = f2b(ff[1]); o.z = f2b(ff[2]); o.w = f2b(ff[3]);
            *(ushort4*)&Al[r * LSTR + c4 * 4] = o;
        }
    } else {                   // AGG bf16 + fused BN + ReLU
        const uint4* Ag = (const uint4*)A;
        for (int it = 0; it < 4; ++it) {
            int idx = tid + it * 256;
            int r = idx >> 4, cc = idx & 15;
            int gr = row0 + r;
            uint4 v; v.x = v.y = v.z = v.w = 0u;
            if (gr < n) v = Ag[(size_t)gr * 16 + cc];
            unsigned short hu[8]; *(uint4*)hu = v;
            unsigned short ou[8];
#pragma unroll
            for (int j = 0; j < 8; ++j) {
                int f = cc * 8 + j;
                float x = b2f(hu[j]) * scale[f] + shift[f];
                ou[j] = f2b(x > 0.f ? x : 0.f);
            }
            *(uint4*)&Al[r * LSTR + cc * 8] = *(uint4*)ou;
        }
    }
    __syncthreads();

    int wave = tid >> 6, lane = tid & 63;
    int m = lane & 15, quad = lane >> 4;

    bf16x8 afr[4];
#pragma unroll
    for (int kc = 0; kc < 4; ++kc)
        afr[kc] = *(const bf16x8*)&Al[(wave * 16 + m) * LSTR + kc * 32 + quad * 8];

    float dv[4];
#pragma unroll
    for (int i2 = 0; i2 < 4; ++i2) {
        int gr = row0 + wave * 16 + quad * 4 + i2;
        dv[i2] = (gr < n) ? dinv[gr] : 0.f;
    }

    for (int t = 0; t < 8; ++t) {
        f32x4 acc = {0.f, 0.f, 0.f, 0.f};
#pragma unroll
        for (int kc = 0; kc < 4; ++kc) {
            bf16x8 bfr = *(const bf16x8*)&Wl[(t * 16 + m) * LSTR + kc * 32 + quad * 8];
            acc = __builtin_amdgcn_mfma_f32_16x16x32_bf16(afr[kc], bfr, acc, 0, 0, 0);
        }
        int f = t * 16 + m;
        int slice = f >> 5, col = f & 31;
#pragma unroll
        for (int i2 = 0; i2 < 4; ++i2) {
            int gr = row0 + wave * 16 + quad * 4 + i2;
            if (gr < n) C[(size_t)slice * sstride + (size_t)gr * 32 + col] = f2b(acc[i2] * dv[i2]);
        }
    }
}

// ---------------- aggregation, slice-tiled for L2 residency + fused stats + fused bn_fin ----------------
// Hb slice-major: 4 slices x [N x 32 feats] (3.2 MB each < 4 MB per-XCD L2).
// 16 groups x 4 lanes; lane gathers 16B (8 bf16). Group 15 adds the self-loop.
__global__ __launch_bounds__(256) void agg_stats(
    const unsigned short* __restrict__ Hs, const int4* __restrict__ meta,
    const int* __restrict__ csr, unsigned short* __restrict__ AGG,
    float* __restrict__ colsum, float* __restrict__ colsq,
    float* __restrict__ scale, float* __restrict__ shift,
    const unsigned short* __restrict__ gam, const unsigned short* __restrict__ bet,
    const int* __restrict__ flag, int* __restrict__ ticket,
    float invn, int n, int sstride) {
    int tid = threadIdx.x;
    int wave = tid >> 6, lane = tid & 63;
    int g = lane >> 2, q = lane & 3;

    __shared__ float sh[4][64];

    for (int slice = 0; slice < 4; ++slice) {
        const unsigned short* base = Hs + (size_t)slice * sstride;
        float s1[8], s2[8];
#pragma unroll
        for (int j = 0; j < 8; ++j) { s1[j] = 0.f; s2[j] = 0.f; }

        for (int i = blockIdx.x * 4 + wave; i < n; i += gridDim.x * 4) {
            int4 mt = meta[i];
            int s0 = mt.x, c = mt.y;
            float di = __int_as_float(mt.z);
            float acc[8];
#pragma unroll
            for (int j = 0; j < 8; ++j) acc[j] = 0.f;

            if (g == 15) {   // self-loop (pre-scaled row)
                uint4 a4 = *(const uint4*)&base[(size_t)i * 32 + q * 8];
                unsigned short au[8]; *(uint4*)au = a4;
#pragma unroll
                for (int j = 0; j < 8; ++j) acc[j] += b2f(au[j]);
            }

            for (int t = g; t < c; t += 16) {
                int s = __builtin_nontemporal_load(&csr[s0 + t]);
                uint4 a4 = *(const uint4*)&base[(size_t)s * 32 + q * 8];
                unsigned short au[8]; *(uint4*)au = a4;
#pragma unroll
                for (int j = 0; j < 8; ++j) acc[j] += b2f(au[j]);
            }

#pragma unroll
            for (int j = 0; j < 8; ++j) {     // reduce across 16 groups (lane bits 2..5)
                acc[j] += __shfl_xor(acc[j], 4, 64);
                acc[j] += __shfl_xor(acc[j], 8, 64);
                acc[j] += __shfl_xor(acc[j], 16, 64);
                acc[j] += __shfl_xor(acc[j], 32, 64);
                acc[j] *= di;
            }
            if (g == 0) {
                unsigned short ou[8];
#pragma unroll
                for (int j = 0; j < 8; ++j) {
                    float v = acc[j];
                    ou[j] = f2b(v);
                    s1[j] += v; s2[j] += v * v;
                }
                *(uint4*)&AGG[(size_t)i * 128 + slice * 32 + q * 8] = *(uint4*)ou;
            }
        }

        // flush this slice's stats
        if (g == 0) {
#pragma unroll
            for (int j = 0; j < 8; ++j) {
                sh[wave][q * 8 + j] = s1[j];
                sh[wave][32 + q * 8 + j] = s2[j];
            }
        }
        __syncthreads();
        if (tid < 64) {
            float a = sh[0][tid] + sh[1][tid] + sh[2][tid] + sh[3][tid];
            if (tid < 32) atomicAdd(&colsum[slice * 32 + tid], a);
            else          atomicAdd(&colsq[slice * 32 + tid - 32], a);
        }
        __syncthreads();
    }

    // last block finalizes BN (ticket pattern, device-scope)
    __threadfence();
    __shared__ int lastf;
    if (tid == 0) lastf = (atomicAdd(ticket, 1) == gridDim.x - 1) ? 1 : 0;
    __syncthreads();
    if (lastf) {
        __threadfence();
        if (tid < 128) {
            float cs = atomicAdd(&colsum[tid], 0.f);   // coherent read
            float cq = atomicAdd(&colsq[tid], 0.f);
            float gv, bv;
            if (flag[0]) { gv = b2f(gam[tid]);            bv = b2f(bet[tid]); }
            else         { gv = ((const float*)gam)[tid]; bv = ((const float*)bet)[tid]; }
            float sc, sf;
            if (!finitef(cs) || !finitef(cq)) { sc = 0.f; sf = 150.f; }
            else {
                float mu = cs * invn;
                float var = cq * invn - mu * mu;
                var = var < 0.f ? 0.f : var;
                float rstd = rsqrtf(var + 1e-5f);
                sc = gv * rstd;
                sf = bv - mu * sc;
            }
            scale[tid] = sc;
            shift[tid] = sf;
            colsum[tid] = 0.f;                         // ready for next layer
            colsq[tid] = 0.f;
        }
        if (tid == 0) *ticket = 0;
    }
}

// ---------------- final BN+ReLU to fp32 d_out, 8 elems/thread ----------------
__global__ void bn_apply_f32(const unsigned short* __restrict__ AGG, const float* __restrict__ scale,
                             const float* __restrict__ shift, float* __restrict__ out, int nchunk) {
    int i = blockIdx.x * 256 + threadIdx.x;
    if (i >= nchunk) return;
    int base = i * 8;
    int f0 = base & 127;
    uint4 hv = *(const uint4*)&AGG[base];
    unsigned short hu[8]; *(uint4*)hu = hv;
    float o[8];
#pragma unroll
    for (int j = 0; j < 8; ++j) {
        float v = b2f(hu[j]) * scale[f0 + j] + shift[f0 + j];
        o[j] = v > 0.f ? v : 0.f;
    }
    *(float4*)&out[base] = *(float4*)&o[0];
    *(float4*)&out[base + 4] = *(float4*)&o[4];
}

// ---------------- launch ----------------
extern "C" void kernel_launch(void* const* d_in, const int* in_sizes, int n_in,
                              void* d_out, int out_size, void* d_ws, size_t ws_size,
                              hipStream_t stream) {
    const unsigned short* X0 = (const unsigned short*)d_in[0];
    const int* ei = (const int*)d_in[1];
    const unsigned short* W1 = (const unsigned short*)d_in[2];
    const unsigned short* W2 = (const unsigned short*)d_in[4];
    const unsigned short* g1 = (const unsigned short*)d_in[6];
    const unsigned short* be1 = (const unsigned short*)d_in[7];
    const unsigned short* g2 = (const unsigned short*)d_in[8];
    const unsigned short* be2 = (const unsigned short*)d_in[9];
    float* OUT = (float*)d_out;

    int N = in_sizes[0] / HDIM;
    int E = in_sizes[1] / 2;
    int total = N * HDIM;
    int applyb = (total + 255) / 256;

    bool ok = (n_in == 10) && (N > 0) && (in_sizes[0] == N * HDIM) && (E > 0)
           && (in_sizes[2] == HDIM * HDIM) && (in_sizes[4] == HDIM * HDIM)
           && (in_sizes[6] == HDIM) && (in_sizes[9] == HDIM) && (out_size == total)
           && (N <= 65536);
    if (!ok) { fill_f32<<<applyb, 256, 0, stream>>>(OUT, total, -100.0f); return; }

    size_t need = (size_t)N * 28 + 2048 + 64 + 16 + 1024 + (size_t)E * 12
                + (size_t)total * 4 + 65536 + 16 + 1024;
    if (ws_size < need) { fill_f32<<<applyb, 256, 0, stream>>>(OUT, total, -300.0f); return; }

    char* w = (char*)d_ws;
    int* cnt = (int*)w;       w += (size_t)N * 4;       // [zero region: cnt|stats|ticket]
    float* stats = (float*)w; w += 2048;                // colsum|colsq|scale|shift
    int* ticket = (int*)w;    w += 64;
    int* flags = (int*)w;     w += 16;                  // NOT zeroed (prep writes it)
    int* bsum = (int*)w;      w += 1024;
    float* dinv = (float*)w;  w += (size_t)N * 4;
    int* cursor = (int*)w;    w += (size_t)N * 4;
    w = (char*)(((uintptr_t)w + 15) & ~(uintptr_t)15);
    int4* meta = (int4*)w;    w += (size_t)N * 16;
    int* s32 = (int*)w;       w += (size_t)E * 4;
    int* d32 = (int*)w;       w += (size_t)E * 4;
    int* csr = (int*)w;       w += (size_t)E * 4;
    w = (char*)(((uintptr_t)w + 255) & ~(uintptr_t)255);
    unsigned short* Hs = (unsigned short*)w;  w += (size_t)total * 2;   // slice-major
    unsigned short* AGG = (unsigned short*)w; w += (size_t)total * 2;   // node-major
    unsigned short* Wt1 = (unsigned short*)w; w += (size_t)HDIM * HDIM * 2;
    unsigned short* Wt2 = (unsigned short*)w; w += (size_t)HDIM * HDIM * 2;

    float* colsum = stats;
    float* colsq = stats + 128;
    float* scale = stats + 256;
    float* shift = stats + 384;

    int nb = (N + 255) / 256;
    int ebl = (E + 255) / 256;
    int gemmb = (N + 63) / 64;
    int sstride = N * 32;                 // ushorts per slice
    float invn = 1.0f / (float)N;
    int zcount = N + 512 + 16;            // cnt + stats floats + ticket ints

    prep<<<128 + (zcount + 255) / 256, 256, 0, stream>>>(X0, W1, W2, Wt1, Wt2, cnt, zcount, flags);
    edges_norm<<<ebl, 256, 0, stream>>>(ei, s32, d32, cnt, E, N);
    scan1<<<nb, 256, 0, stream>>>(cnt, bsum, dinv, N);
    scan3<<<nb, 256, 0, stream>>>(cnt, bsum, meta, cursor, N, nb);
    scatter_k<<<ebl, 256, 0, stream>>>(s32, d32, cursor, csr, E);

    // layer 1
    gemm_mfma<<<gemmb, 256, 0, stream>>>(X0, Wt1, Hs, flags, -1, scale, shift, dinv, N, sstride);
    agg_stats<<<2048, 256, 0, stream>>>(Hs, meta, csr, AGG, colsum, colsq, scale, shift,
                                        g1, be1, flags, ticket, invn, N, sstride);
    // layer 2 (BN+ReLU fused into gemm A-staging)
    gemm_mfma<<<gemmb, 256, 0, stream>>>(AGG, Wt2, Hs, flags, 2, scale, shift, dinv, N, sstride);
    agg_stats<<<2048, 256, 0, stream>>>(Hs, meta, csr, AGG, colsum, colsq, scale, shift,
                                        g2, be2, flags, ticket, invn, N, sstride);
    bn_apply_f32<<<(total / 8 + 255) / 256, 256, 0, stream>>>(AGG, scale, shift, OUT, total / 8);
}

// Round 10
// 640.743 us; speedup vs baseline: 1.4526x; 1.4526x over previous
//
#include <hip/hip_runtime.h>

// ---------------- bf16 helpers (raw ushort storage) ----------------
__device__ __forceinline__ float b2f(unsigned short u) {
    union { unsigned int i; float f; } x; x.i = ((unsigned int)u) << 16; return x.f;
}
__device__ __forceinline__ unsigned short f2b(float f) {
    union { float f; unsigned int i; } x; x.f = f;
    unsigned int r = x.i + 0x7fffu + ((x.i >> 16) & 1u);   // RNE
    return (unsigned short)(r >> 16);
}
__device__ __forceinline__ bool finitef(float x) {
    union { float f; unsigned int u; } c; c.f = x;
    return ((c.u >> 23) & 0xffu) != 0xffu;
}

typedef __attribute__((ext_vector_type(8))) __bf16 bf16x8;
typedef __attribute__((ext_vector_type(4))) float f32x4;

#define HDIM 128
#define LSTR 136

// ---------------- failure-path fill ----------------
__global__ void fill_f32(float* p, int n, float v) {
    int i = blockIdx.x * 256 + threadIdx.x;
    if (i < n) p[i] = v;
}

// ---------------- prep: detect dtype + normalize/transpose W1,W2 + zero cnt/stats/ticket ----------------
__global__ void prep(const unsigned short* __restrict__ X0,
                     const unsigned short* __restrict__ W1, const unsigned short* __restrict__ W2,
                     unsigned short* __restrict__ Wt1, unsigned short* __restrict__ Wt2,
                     int* __restrict__ zbase, int zcount, int* __restrict__ flags) {
    int bid = blockIdx.x, tid = threadIdx.x;
    if (bid < 128) {
        __shared__ int sane;
        if (tid == 0) sane = 0;
        __syncthreads();
        unsigned short u = X0[2 * tid];
        int e = (u >> 7) & 0xff;
        if (e >= 100 && e <= 140) atomicAdd(&sane, 1);
        __syncthreads();
        int isbf = (sane >= 128) ? 1 : 0;
        if (bid == 0 && tid == 0) flags[0] = isbf;
        int idx = bid * 256 + tid;          // 0..32767
        const unsigned short* src; unsigned short* dst; int l;
        if (idx < 16384) { src = W1; dst = Wt1; l = idx; }
        else             { src = W2; dst = Wt2; l = idx - 16384; }
        int k = l >> 7, c = l & 127;
        unsigned short v = isbf ? src[l] : f2b(((const float*)src)[l]);
        dst[c * 128 + k] = v;               // Wt[n][k]
    } else {
        int i = (bid - 128) * 256 + tid;
        if (i < zcount) zbase[i] = 0;
    }
}

// ---------------- edges: degree histogram only (dst clamped) ----------------
__global__ void edges_norm(const int* __restrict__ ei, int* __restrict__ cnt, int E, int N) {
    __shared__ int sh;
    if (threadIdx.x == 0) {
        int acc = 0;
        for (int k = 1; k < 129; k += 2) acc |= ei[k];  // int64 => high words all 0
        sh = (acc == 0) ? 1 : 0;
    }
    __syncthreads();
    int is64 = sh;
    int e = blockIdx.x * 256 + threadIdx.x;
    if (e < E) {
        int d = is64 ? ei[2 * (size_t)E + 2 * (size_t)e] : ei[(size_t)E + e];
        d = d < 0 ? 0 : (d >= N ? N - 1 : d);
        atomicAdd(&cnt[d], 1);
    }
}

// ---------------- scan1: per-block sums + dinv ----------------
__global__ void scan1(const int* __restrict__ cnt, int* __restrict__ bsum,
                      float* __restrict__ dinv, int n) {
    __shared__ int sh[256];
    int t = threadIdx.x;
    int i = blockIdx.x * 256 + t;
    int v = (i < n) ? cnt[i] : 0;
    sh[t] = v;
    if (i < n) dinv[i] = rsqrtf((float)v + 1.0f);
    __syncthreads();
    for (int s = 128; s > 0; s >>= 1) {
        if (t < s) sh[t] += sh[t + s];
        __syncthreads();
    }
    if (t == 0) bsum[blockIdx.x] = sh[0];
}

// ---------------- scan3: in-block bsum prefix + meta + cursor ----------------
__global__ void scan3(const int* __restrict__ cnt, const int* __restrict__ bsum,
                      int4* __restrict__ meta, int* __restrict__ cursor, int n, int nblk) {
    __shared__ int sb[256];
    __shared__ int sh[256];
    int t = threadIdx.x;
    sb[t] = (t < nblk) ? bsum[t] : 0;
    __syncthreads();
    for (int off = 1; off < 256; off <<= 1) {
        int v = (t >= off) ? sb[t - off] : 0;
        __syncthreads();
        sb[t] += v;
        __syncthreads();
    }
    int bpre = (blockIdx.x == 0) ? 0 : sb[blockIdx.x - 1];

    int i = blockIdx.x * 256 + t;
    int v = (i < n) ? cnt[i] : 0;
    sh[t] = v;
    __syncthreads();
    for (int off = 1; off < 256; off <<= 1) {
        int a = (t >= off) ? sh[t - off] : 0;
        __syncthreads();
        sh[t] += a;
        __syncthreads();
    }
    if (i < n) {
        int excl = sh[t] - v + bpre;
        float dv = rsqrtf((float)v + 1.0f);
        meta[i] = make_int4(excl, v, __float_as_int(dv), 0);
        cursor[i] = excl;
    }
}

// ---------------- scatter: reads edge_index directly (clamped), fills csr ----------------
__global__ void scatter_k(const int* __restrict__ ei, int* __restrict__ cursor,
                          int* __restrict__ csr, int E, int N) {
    __shared__ int sh;
    if (threadIdx.x == 0) {
        int acc = 0;
        for (int k = 1; k < 129; k += 2) acc |= ei[k];
        sh = (acc == 0) ? 1 : 0;
    }
    __syncthreads();
    int is64 = sh;
    int e = blockIdx.x * 256 + threadIdx.x;
    if (e < E) {
        int s, d;
        if (is64) { s = ei[2 * (size_t)e]; d = ei[2 * (size_t)E + 2 * (size_t)e]; }
        else      { s = ei[e];             d = ei[(size_t)E + e]; }
        s = s < 0 ? 0 : (s >= N ? N - 1 : s);
        d = d < 0 ? 0 : (d >= N ? N - 1 : d);
        int slot = atomicAdd(&cursor[d], 1);
        csr[slot] = s;
    }
}

// ---------------- GEMM (MFMA 16x16x32 bf16): C[n,128] = dinv[n] * (A[n,128] @ W) ----------------
__global__ __launch_bounds__(256) void gemm_mfma(
    const unsigned short* __restrict__ A, const unsigned short* __restrict__ Wt,
    unsigned short* __restrict__ C, const int* __restrict__ aflag, int mode,
    const float* __restrict__ scale, const float* __restrict__ shift,
    const float* __restrict__ dinv, int n) {
    __shared__ __align__(16) unsigned short Wl[128 * LSTR];
    __shared__ __align__(16) unsigned short Al[64 * LSTR];
    int tid = threadIdx.x;
    int row0 = blockIdx.x * 64;

    const uint4* Wg = (const uint4*)Wt;
#pragma unroll
    for (int it = 0; it < 8; ++it) {
        int idx = tid + it * 256;
        int nn = idx >> 4, k8 = idx & 15;
        *(uint4*)&Wl[nn * LSTR + k8 * 8] = Wg[idx];
    }

    int amode = (mode == 2) ? 2 : aflag[0];
    if (amode == 1) {
        const uint4* Ag = (const uint4*)A;
        for (int it = 0; it < 4; ++it) {
            int idx = tid + it * 256;
            int r = idx >> 4, cc = idx & 15;
            int gr = row0 + r;
            uint4 v; v.x = v.y = v.z = v.w = 0u;
            if (gr < n) v = Ag[(size_t)gr * 16 + cc];
            *(uint4*)&Al[r * LSTR + cc * 8] = v;
        }
    } else if (amode == 0) {
        const uint4* Af = (const uint4*)A;
        for (int it = 0; it < 8; ++it) {
            int idx = tid + it * 256;
            int r = idx >> 5, c4 = idx & 31;
            int gr = row0 + r;
            uint4 v; v.x = v.y = v.z = v.w = 0u;
            if (gr < n) v = Af[(size_t)gr * 32 + c4];
            float ff[4]; *(uint4*)ff = v;
            ushort4 o;
            o.x = f2b(ff[0]); o.y = f2b(ff[1]); o.z = f2b(ff[2]); o.w = f2b(ff[3]);
            *(ushort4*)&Al[r * LSTR + c4 * 4] = o;
        }
    } else {                   // AGG bf16 + fused BN + ReLU
        const uint4* Ag = (const uint4*)A;
        for (int it = 0; it < 4; ++it) {
            int idx = tid + it * 256;
            int r = idx >> 4, cc = idx & 15;
            int gr = row0 + r;
            uint4 v; v.x = v.y = v.z = v.w = 0u;
            if (gr < n) v = Ag[(size_t)gr * 16 + cc];
            unsigned short hu[8]; *(uint4*)hu = v;
            unsigned short ou[8];
#pragma unroll
            for (int j = 0; j < 8; ++j) {
                int f = cc * 8 + j;
                float x = b2f(hu[j]) * scale[f] + shift[f];
                ou[j] = f2b(x > 0.f ? x : 0.f);
            }
            *(uint4*)&Al[r * LSTR + cc * 8] = *(uint4*)ou;
        }
    }
    __syncthreads();

    int wave = tid >> 6, lane = tid & 63;
    int m = lane & 15, quad = lane >> 4;

    bf16x8 afr[4];
#pragma unroll
    for (int kc = 0; kc < 4; ++kc)
        afr[kc] = *(const bf16x8*)&Al[(wave * 16 + m) * LSTR + kc * 32 + quad * 8];

    float dv[4];
#pragma unroll
    for (int i2 = 0; i2 < 4; ++i2) {
        int gr = row0 + wave * 16 + quad * 4 + i2;
        dv[i2] = (gr < n) ? dinv[gr] : 0.f;
    }

    for (int t = 0; t < 8; ++t) {
        f32x4 acc = {0.f, 0.f, 0.f, 0.f};
#pragma unroll
        for (int kc = 0; kc < 4; ++kc) {
            bf16x8 bfr = *(const bf16x8*)&Wl[(t * 16 + m) * LSTR + kc * 32 + quad * 8];
            acc = __builtin_amdgcn_mfma_f32_16x16x32_bf16(afr[kc], bfr, acc, 0, 0, 0);
        }
#pragma unroll
        for (int i2 = 0; i2 < 4; ++i2) {
            int gr = row0 + wave * 16 + quad * 4 + i2;
            if (gr < n) C[(size_t)gr * 128 + t * 16 + m] = f2b(acc[i2] * dv[i2]);
        }
    }
}

// ---------------- aggregation (r8 core) + fused BN finalize (ticket) ----------------
// Hb rows pre-scaled by dinv[src]: out[i] = dinv[i] * (Hb[i] + sum Hb[csr]).
// 1 wave/node; 4 groups x 16 lanes; lane gathers uint4 (8 bf16); 4-deep index prefetch.
__global__ __launch_bounds__(256) void agg_stats(
    const unsigned short* __restrict__ Hb, const int4* __restrict__ meta,
    const int* __restrict__ csr, unsigned short* __restrict__ AGG,
    float* __restrict__ colsum, float* __restrict__ colsq,
    float* __restrict__ scale, float* __restrict__ shift,
    const unsigned short* __restrict__ gam, const unsigned short* __restrict__ bet,
    const int* __restrict__ flag, int* __restrict__ ticket,
    float invn, int n) {
    int tid = threadIdx.x;
    int wave = tid >> 6, lane = tid & 63;
    int g = lane >> 4, q = lane & 15;

    float s1[8], s2[8];
#pragma unroll
    for (int j = 0; j < 8; ++j) { s1[j] = 0.f; s2[j] = 0.f; }

    for (int i = blockIdx.x * 4 + wave; i < n; i += gridDim.x * 4) {
        int4 mt = meta[i];                       // {start, cnt, dinv_bits}
        int s0 = mt.x, c = mt.y;
        float di = __int_as_float(mt.z);
        float acc[8];
#pragma unroll
        for (int j = 0; j < 8; ++j) acc[j] = 0.f;

        if (g == 0) {   // self-loop (pre-scaled row)
            uint4 a4 = *(const uint4*)&Hb[(size_t)i * 128 + q * 8];
            unsigned short au[8]; *(uint4*)au = a4;
#pragma unroll
            for (int j = 0; j < 8; ++j) acc[j] += b2f(au[j]);
        }

        int t = g;
        for (; t + 12 < c; t += 16) {            // 4 independent gather chains
            int sA = csr[s0 + t];
            int sB = csr[s0 + t + 4];
            int sC = csr[s0 + t + 8];
            int sD = csr[s0 + t + 12];
            uint4 a4 = *(const uint4*)&Hb[(size_t)sA * 128 + q * 8];
            uint4 b4 = *(const uint4*)&Hb[(size_t)sB * 128 + q * 8];
            uint4 c4 = *(const uint4*)&Hb[(size_t)sC * 128 + q * 8];
            uint4 d4 = *(const uint4*)&Hb[(size_t)sD * 128 + q * 8];
            unsigned short au[8]; *(uint4*)au = a4;
            unsigned short bu[8]; *(uint4*)bu = b4;
            unsigned short cu[8]; *(uint4*)cu = c4;
            unsigned short du[8]; *(uint4*)du = d4;
#pragma unroll
            for (int j = 0; j < 8; ++j)
                acc[j] += (b2f(au[j]) + b2f(bu[j])) + (b2f(cu[j]) + b2f(du[j]));
        }
        for (; t < c; t += 4) {
            int sA = csr[s0 + t];
            uint4 a4 = *(const uint4*)&Hb[(size_t)sA * 128 + q * 8];
            unsigned short au[8]; *(uint4*)au = a4;
#pragma unroll
            for (int j = 0; j < 8; ++j) acc[j] += b2f(au[j]);
        }

#pragma unroll
        for (int j = 0; j < 8; ++j) {
            acc[j] += __shfl_xor(acc[j], 16, 64);
            acc[j] += __shfl_xor(acc[j], 32, 64);
            acc[j] *= di;
        }
        if (g == 0) {
            unsigned short ou[8];
#pragma unroll
            for (int j = 0; j < 8; ++j) {
                float v = acc[j];
                ou[j] = f2b(v);
                s1[j] += v; s2[j] += v * v;
            }
            *(uint4*)&AGG[(size_t)i * 128 + q * 8] = *(uint4*)ou;
        }
    }

    __shared__ float sh[4][256];
    if (g == 0) {
#pragma unroll
        for (int j = 0; j < 8; ++j) {
            sh[wave][q * 8 + j] = s1[j];
            sh[wave][128 + q * 8 + j] = s2[j];
        }
    }
    __syncthreads();
    if (tid < 128) {
        float a = sh[0][tid] + sh[1][tid] + sh[2][tid] + sh[3][tid];
        float b = sh[0][128 + tid] + sh[1][128 + tid] + sh[2][128 + tid] + sh[3][128 + tid];
        atomicAdd(&colsum[tid], a);
        atomicAdd(&colsq[tid], b);
    }

    // last block finalizes BN (ticket pattern, device-scope)
    __threadfence();
    __shared__ int lastf;
    if (tid == 0) lastf = (atomicAdd(ticket, 1) == gridDim.x - 1) ? 1 : 0;
    __syncthreads();
    if (lastf) {
        __threadfence();
        if (tid < 128) {
            float cs = atomicAdd(&colsum[tid], 0.f);   // coherent read
            float cq = atomicAdd(&colsq[tid], 0.f);
            float gv, bv;
            if (flag[0]) { gv = b2f(gam[tid]);            bv = b2f(bet[tid]); }
            else         { gv = ((const float*)gam)[tid]; bv = ((const float*)bet)[tid]; }
            float sc, sf;
            if (!finitef(cs) || !finitef(cq)) { sc = 0.f; sf = 150.f; }
            else {
                float mu = cs * invn;
                float var = cq * invn - mu * mu;
                var = var < 0.f ? 0.f : var;
                float rstd = rsqrtf(var + 1e-5f);
                sc = gv * rstd;
                sf = bv - mu * sc;
            }
            scale[tid] = sc;
            shift[tid] = sf;
            colsum[tid] = 0.f;                         // ready for next layer
            colsq[tid] = 0.f;
        }
        if (tid == 0) *ticket = 0;
    }
}

// ---------------- final BN+ReLU to fp32 d_out, 8 elems/thread ----------------
__global__ void bn_apply_f32(const unsigned short* __restrict__ AGG, const float* __restrict__ scale,
                             const float* __restrict__ shift, float* __restrict__ out, int nchunk) {
    int i = blockIdx.x * 256 + threadIdx.x;
    if (i >= nchunk) return;
    int base = i * 8;
    int f0 = base & 127;
    uint4 hv = *(const uint4*)&AGG[base];
    unsigned short hu[8]; *(uint4*)hu = hv;
    float o[8];
#pragma unroll
    for (int j = 0; j < 8; ++j) {
        float v = b2f(hu[j]) * scale[f0 + j] + shift[f0 + j];
        o[j] = v > 0.f ? v : 0.f;
    }
    *(float4*)&out[base] = *(float4*)&o[0];
    *(float4*)&out[base + 4] = *(float4*)&o[4];
}

// ---------------- launch ----------------
extern "C" void kernel_launch(void* const* d_in, const int* in_sizes, int n_in,
                              void* d_out, int out_size, void* d_ws, size_t ws_size,
                              hipStream_t stream) {
    const unsigned short* X0 = (const unsigned short*)d_in[0];
    const int* ei = (const int*)d_in[1];
    const unsigned short* W1 = (const unsigned short*)d_in[2];
    const unsigned short* W2 = (const unsigned short*)d_in[4];
    const unsigned short* g1 = (const unsigned short*)d_in[6];
    const unsigned short* be1 = (const unsigned short*)d_in[7];
    const unsigned short* g2 = (const unsigned short*)d_in[8];
    const unsigned short* be2 = (const unsigned short*)d_in[9];
    float* OUT = (float*)d_out;

    int N = in_sizes[0] / HDIM;
    int E = in_sizes[1] / 2;
    int total = N * HDIM;
    int applyb = (total + 255) / 256;

    bool ok = (n_in == 10) && (N > 0) && (in_sizes[0] == N * HDIM) && (E > 0)
           && (in_sizes[2] == HDIM * HDIM) && (in_sizes[4] == HDIM * HDIM)
           && (in_sizes[6] == HDIM) && (in_sizes[9] == HDIM) && (out_size == total)
           && (N <= 65536);
    if (!ok) { fill_f32<<<applyb, 256, 0, stream>>>(OUT, total, -100.0f); return; }

    size_t need = (size_t)N * 28 + 2048 + 64 + 16 + 1024 + (size_t)E * 4
                + (size_t)total * 4 + 65536 + 512;
    if (ws_size < need) { fill_f32<<<applyb, 256, 0, stream>>>(OUT, total, -300.0f); return; }

    char* w = (char*)d_ws;
    int* cnt = (int*)w;       w += (size_t)N * 4;       // [zero region: cnt|stats|ticket]
    float* stats = (float*)w; w += 2048;                // colsum|colsq|scale|shift
    int* ticket = (int*)w;    w += 64;
    int* flags = (int*)w;     w += 16;                  // written by prep
    int* bsum = (int*)w;      w += 1024;
    float* dinv = (float*)w;  w += (size_t)N * 4;
    int* cursor = (int*)w;    w += (size_t)N * 4;
    w = (char*)(((uintptr_t)w + 15) & ~(uintptr_t)15);
    int4* meta = (int4*)w;    w += (size_t)N * 16;
    int* csr = (int*)w;       w += (size_t)E * 4;
    w = (char*)(((uintptr_t)w + 255) & ~(uintptr_t)255);
    unsigned short* Hb = (unsigned short*)w;  w += (size_t)total * 2;
    unsigned short* AGG = (unsigned short*)w; w += (size_t)total * 2;
    unsigned short* Wt1 = (unsigned short*)w; w += (size_t)HDIM * HDIM * 2;
    unsigned short* Wt2 = (unsigned short*)w; w += (size_t)HDIM * HDIM * 2;

    float* colsum = stats;
    float* colsq = stats + 128;
    float* scale = stats + 256;
    float* shift = stats + 384;

    int nb = (N + 255) / 256;
    int ebl = (E + 255) / 256;
    int gemmb = (N + 63) / 64;
    float invn = 1.0f / (float)N;
    int zcount = N + 512 + 16;

    prep<<<128 + (zcount + 255) / 256, 256, 0, stream>>>(X0, W1, W2, Wt1, Wt2, cnt, zcount, flags);
    edges_norm<<<ebl, 256, 0, stream>>>(ei, cnt, E, N);
    scan1<<<nb, 256, 0, stream>>>(cnt, bsum, dinv, N);
    scan3<<<nb, 256, 0, stream>>>(cnt, bsum, meta, cursor, N, nb);
    scatter_k<<<ebl, 256, 0, stream>>>(ei, cursor, csr, E, N);

    // layer 1
    gemm_mfma<<<gemmb, 256, 0, stream>>>(X0, Wt1, Hb, flags, -1, scale, shift, dinv, N);
    agg_stats<<<2048, 256, 0, stream>>>(Hb, meta, csr, AGG, colsum, colsq, scale, shift,
                                        g1, be1, flags, ticket, invn, N);
    // layer 2 (BN+ReLU fused into gemm A-staging)
    gemm_mfma<<<gemmb, 256, 0, stream>>>(AGG, Wt2, Hb, flags, 2, scale, shift, dinv, N);
    agg_stats<<<2048, 256, 0, stream>>>(Hb, meta, csr, AGG, colsum, colsq, scale, shift,
                                        g2, be2, flags, ticket, invn, N);
    bn_apply_f32<<<(total / 8 + 255) / 256, 256, 0, stream>>>(AGG, scale, shift, OUT, total / 8);
}

// Round 11
// 379.628 us; speedup vs baseline: 2.4517x; 1.6878x over previous
//
#include <hip/hip_runtime.h>

// ---------------- bf16 helpers (raw ushort storage) ----------------
__device__ __forceinline__ float b2f(unsigned short u) {
    union { unsigned int i; float f; } x; x.i = ((unsigned int)u) << 16; return x.f;
}
__device__ __forceinline__ unsigned short f2b(float f) {
    union { float f; unsigned int i; } x; x.f = f;
    unsigned int r = x.i + 0x7fffu + ((x.i >> 16) & 1u);   // RNE
    return (unsigned short)(r >> 16);
}
__device__ __forceinline__ bool finitef(float x) {
    union { float f; unsigned int u; } c; c.f = x;
    return ((c.u >> 23) & 0xffu) != 0xffu;
}

typedef __attribute__((ext_vector_type(8))) __bf16 bf16x8;
typedef __attribute__((ext_vector_type(4))) float f32x4;

#define HDIM 128
#define LSTR 136

// ---------------- failure-path fill ----------------
__global__ void fill_f32(float* p, int n, float v) {
    int i = blockIdx.x * 256 + threadIdx.x;
    if (i < n) p[i] = v;
}

// ---------------- prep: detect dtype + normalize/transpose W1,W2 + zero cnt/stats ----------------
__global__ void prep(const unsigned short* __restrict__ X0,
                     const unsigned short* __restrict__ W1, const unsigned short* __restrict__ W2,
                     unsigned short* __restrict__ Wt1, unsigned short* __restrict__ Wt2,
                     int* __restrict__ zbase, int zcount, int* __restrict__ flags) {
    int bid = blockIdx.x, tid = threadIdx.x;
    if (bid < 128) {
        __shared__ int sane;
        if (tid == 0) sane = 0;
        __syncthreads();
        unsigned short u = X0[2 * tid];
        int e = (u >> 7) & 0xff;
        if (e >= 100 && e <= 140) atomicAdd(&sane, 1);
        __syncthreads();
        int isbf = (sane >= 128) ? 1 : 0;
        if (bid == 0 && tid == 0) flags[0] = isbf;
        int idx = bid * 256 + tid;          // 0..32767
        const unsigned short* src; unsigned short* dst; int l;
        if (idx < 16384) { src = W1; dst = Wt1; l = idx; }
        else             { src = W2; dst = Wt2; l = idx - 16384; }
        int k = l >> 7, c = l & 127;
        unsigned short v = isbf ? src[l] : f2b(((const float*)src)[l]);
        dst[c * 128 + k] = v;               // Wt[n][k]
    } else {
        int i = (bid - 128) * 256 + tid;
        if (i < zcount) zbase[i] = 0;
    }
}

// ---------------- edges: degree histogram only (dst clamped) ----------------
__global__ void edges_norm(const int* __restrict__ ei, int* __restrict__ cnt, int E, int N) {
    __shared__ int sh;
    if (threadIdx.x == 0) {
        int acc = 0;
        for (int k = 1; k < 129; k += 2) acc |= ei[k];  // int64 => high words all 0
        sh = (acc == 0) ? 1 : 0;
    }
    __syncthreads();
    int is64 = sh;
    int e = blockIdx.x * 256 + threadIdx.x;
    if (e < E) {
        int d = is64 ? ei[2 * (size_t)E + 2 * (size_t)e] : ei[(size_t)E + e];
        d = d < 0 ? 0 : (d >= N ? N - 1 : d);
        atomicAdd(&cnt[d], 1);
    }
}

// ---------------- scan1: per-block sums + dinv ----------------
__global__ void scan1(const int* __restrict__ cnt, int* __restrict__ bsum,
                      float* __restrict__ dinv, int n) {
    __shared__ int sh[256];
    int t = threadIdx.x;
    int i = blockIdx.x * 256 + t;
    int v = (i < n) ? cnt[i] : 0;
    sh[t] = v;
    if (i < n) dinv[i] = rsqrtf((float)v + 1.0f);
    __syncthreads();
    for (int s = 128; s > 0; s >>= 1) {
        if (t < s) sh[t] += sh[t + s];
        __syncthreads();
    }
    if (t == 0) bsum[blockIdx.x] = sh[0];
}

// ---------------- scan3: in-block bsum prefix + meta + cursor ----------------
__global__ void scan3(const int* __restrict__ cnt, const int* __restrict__ bsum,
                      int4* __restrict__ meta, int* __restrict__ cursor, int n, int nblk) {
    __shared__ int sb[256];
    __shared__ int sh[256];
    int t = threadIdx.x;
    sb[t] = (t < nblk) ? bsum[t] : 0;
    __syncthreads();
    for (int off = 1; off < 256; off <<= 1) {
        int v = (t >= off) ? sb[t - off] : 0;
        __syncthreads();
        sb[t] += v;
        __syncthreads();
    }
    int bpre = (blockIdx.x == 0) ? 0 : sb[blockIdx.x - 1];

    int i = blockIdx.x * 256 + t;
    int v = (i < n) ? cnt[i] : 0;
    sh[t] = v;
    __syncthreads();
    for (int off = 1; off < 256; off <<= 1) {
        int a = (t >= off) ? sh[t - off] : 0;
        __syncthreads();
        sh[t] += a;
        __syncthreads();
    }
    if (i < n) {
        int excl = sh[t] - v + bpre;
        float dv = rsqrtf((float)v + 1.0f);
        meta[i] = make_int4(excl, v, __float_as_int(dv), 0);
        cursor[i] = excl;
    }
}

// ---------------- scatter: reads edge_index directly (clamped), fills csr ----------------
__global__ void scatter_k(const int* __restrict__ ei, int* __restrict__ cursor,
                          int* __restrict__ csr, int E, int N) {
    __shared__ int sh;
    if (threadIdx.x == 0) {
        int acc = 0;
        for (int k = 1; k < 129; k += 2) acc |= ei[k];
        sh = (acc == 0) ? 1 : 0;
    }
    __syncthreads();
    int is64 = sh;
    int e = blockIdx.x * 256 + threadIdx.x;
    if (e < E) {
        int s, d;
        if (is64) { s = ei[2 * (size_t)e]; d = ei[2 * (size_t)E + 2 * (size_t)e]; }
        else      { s = ei[e];             d = ei[(size_t)E + e]; }
        s = s < 0 ? 0 : (s >= N ? N - 1 : s);
        d = d < 0 ? 0 : (d >= N ? N - 1 : d);
        int slot = atomicAdd(&cursor[d], 1);
        csr[slot] = s;
    }
}

// ---------------- GEMM (MFMA 16x16x32 bf16): C[n,128] = dinv[n] * (A[n,128] @ W) ----------------
__global__ __launch_bounds__(256) void gemm_mfma(
    const unsigned short* __restrict__ A, const unsigned short* __restrict__ Wt,
    unsigned short* __restrict__ C, const int* __restrict__ aflag, int mode,
    const float* __restrict__ scale, const float* __restrict__ shift,
    const float* __restrict__ dinv, int n) {
    __shared__ __align__(16) unsigned short Wl[128 * LSTR];
    __shared__ __align__(16) unsigned short Al[64 * LSTR];
    int tid = threadIdx.x;
    int row0 = blockIdx.x * 64;

    const uint4* Wg = (const uint4*)Wt;
#pragma unroll
    for (int it = 0; it < 8; ++it) {
        int idx = tid + it * 256;
        int nn = idx >> 4, k8 = idx & 15;
        *(uint4*)&Wl[nn * LSTR + k8 * 8] = Wg[idx];
    }

    int amode = (mode == 2) ? 2 : aflag[0];
    if (amode == 1) {
        const uint4* Ag = (const uint4*)A;
        for (int it = 0; it < 4; ++it) {
            int idx = tid + it * 256;
            int r = idx >> 4, cc = idx & 15;
            int gr = row0 + r;
            uint4 v; v.x = v.y = v.z = v.w = 0u;
            if (gr < n) v = Ag[(size_t)gr * 16 + cc];
            *(uint4*)&Al[r * LSTR + cc * 8] = v;
        }
    } else if (amode == 0) {
        const uint4* Af = (const uint4*)A;
        for (int it = 0; it < 8; ++it) {
            int idx = tid + it * 256;
            int r = idx >> 5, c4 = idx & 31;
            int gr = row0 + r;
            uint4 v; v.x = v.y = v.z = v.w = 0u;
            if (gr < n) v = Af[(size_t)gr * 32 + c4];
            float ff[4]; *(uint4*)ff = v;
            ushort4 o;
            o.x = f2b(ff[0]); o.y = f2b(ff[1]); o.z = f2b(ff[2]); o.w = f2b(ff[3]);
            *(ushort4*)&Al[r * LSTR + c4 * 4] = o;
        }
    } else {                   // AGG bf16 + fused BN + ReLU
        const uint4* Ag = (const uint4*)A;
        for (int it = 0; it < 4; ++it) {
            int idx = tid + it * 256;
            int r = idx >> 4, cc = idx & 15;
            int gr = row0 + r;
            uint4 v; v.x = v.y = v.z = v.w = 0u;
            if (gr < n) v = Ag[(size_t)gr * 16 + cc];
            unsigned short hu[8]; *(uint4*)hu = v;
            unsigned short ou[8];
#pragma unroll
            for (int j = 0; j < 8; ++j) {
                int f = cc * 8 + j;
                float x = b2f(hu[j]) * scale[f] + shift[f];
                ou[j] = f2b(x > 0.f ? x : 0.f);
            }
            *(uint4*)&Al[r * LSTR + cc * 8] = *(uint4*)ou;
        }
    }
    __syncthreads();

    int wave = tid >> 6, lane = tid & 63;
    int m = lane & 15, quad = lane >> 4;

    bf16x8 afr[4];
#pragma unroll
    for (int kc = 0; kc < 4; ++kc)
        afr[kc] = *(const bf16x8*)&Al[(wave * 16 + m) * LSTR + kc * 32 + quad * 8];

    float dv[4];
#pragma unroll
    for (int i2 = 0; i2 < 4; ++i2) {
        int gr = row0 + wave * 16 + quad * 4 + i2;
        dv[i2] = (gr < n) ? dinv[gr] : 0.f;
    }

    for (int t = 0; t < 8; ++t) {
        f32x4 acc = {0.f, 0.f, 0.f, 0.f};
#pragma unroll
        for (int kc = 0; kc < 4; ++kc) {
            bf16x8 bfr = *(const bf16x8*)&Wl[(t * 16 + m) * LSTR + kc * 32 + quad * 8];
            acc = __builtin_amdgcn_mfma_f32_16x16x32_bf16(afr[kc], bfr, acc, 0, 0, 0);
        }
#pragma unroll
        for (int i2 = 0; i2 < 4; ++i2) {
            int gr = row0 + wave * 16 + quad * 4 + i2;
            if (gr < n) C[(size_t)gr * 128 + t * 16 + m] = f2b(acc[i2] * dv[i2]);
        }
    }
}

// ---------------- aggregation + fused BN column stats (r8 core, NO fence/ticket tail) ----------------
// Hb rows pre-scaled by dinv[src]: out[i] = dinv[i] * (Hb[i] + sum Hb[csr]).
// 1 wave/node; 4 groups x 16 lanes; lane gathers uint4 (8 bf16); 4-deep index prefetch.
__global__ __launch_bounds__(256) void agg_stats(
    const unsigned short* __restrict__ Hb, const int4* __restrict__ meta,
    const int* __restrict__ csr, unsigned short* __restrict__ AGG,
    float* __restrict__ colsum, float* __restrict__ colsq, int n) {
    int tid = threadIdx.x;
    int wave = tid >> 6, lane = tid & 63;
    int g = lane >> 4, q = lane & 15;

    float s1[8], s2[8];
#pragma unroll
    for (int j = 0; j < 8; ++j) { s1[j] = 0.f; s2[j] = 0.f; }

    for (int i = blockIdx.x * 4 + wave; i < n; i += gridDim.x * 4) {
        int4 mt = meta[i];                       // {start, cnt, dinv_bits}
        int s0 = mt.x, c = mt.y;
        float di = __int_as_float(mt.z);
        float acc[8];
#pragma unroll
        for (int j = 0; j < 8; ++j) acc[j] = 0.f;

        if (g == 0) {   // self-loop (pre-scaled row)
            uint4 a4 = *(const uint4*)&Hb[(size_t)i * 128 + q * 8];
            unsigned short au[8]; *(uint4*)au = a4;
#pragma unroll
            for (int j = 0; j < 8; ++j) acc[j] += b2f(au[j]);
        }

        int t = g;
        for (; t + 12 < c; t += 16) {            // 4 independent gather chains
            int sA = csr[s0 + t];
            int sB = csr[s0 + t + 4];
            int sC = csr[s0 + t + 8];
            int sD = csr[s0 + t + 12];
            uint4 a4 = *(const uint4*)&Hb[(size_t)sA * 128 + q * 8];
            uint4 b4 = *(const uint4*)&Hb[(size_t)sB * 128 + q * 8];
            uint4 c4 = *(const uint4*)&Hb[(size_t)sC * 128 + q * 8];
            uint4 d4 = *(const uint4*)&Hb[(size_t)sD * 128 + q * 8];
            unsigned short au[8]; *(uint4*)au = a4;
            unsigned short bu[8]; *(uint4*)bu = b4;
            unsigned short cu[8]; *(uint4*)cu = c4;
            unsigned short du[8]; *(uint4*)du = d4;
#pragma unroll
            for (int j = 0; j < 8; ++j)
                acc[j] += (b2f(au[j]) + b2f(bu[j])) + (b2f(cu[j]) + b2f(du[j]));
        }
        for (; t < c; t += 4) {
            int sA = csr[s0 + t];
            uint4 a4 = *(const uint4*)&Hb[(size_t)sA * 128 + q * 8];
            unsigned short au[8]; *(uint4*)au = a4;
#pragma unroll
            for (int j = 0; j < 8; ++j) acc[j] += b2f(au[j]);
        }

#pragma unroll
        for (int j = 0; j < 8; ++j) {
            acc[j] += __shfl_xor(acc[j], 16, 64);
            acc[j] += __shfl_xor(acc[j], 32, 64);
            acc[j] *= di;
        }
        if (g == 0) {
            unsigned short ou[8];
#pragma unroll
            for (int j = 0; j < 8; ++j) {
                float v = acc[j];
                ou[j] = f2b(v);
                s1[j] += v; s2[j] += v * v;
            }
            *(uint4*)&AGG[(size_t)i * 128 + q * 8] = *(uint4*)ou;
        }
    }

    __shared__ float sh[4][256];
    if (g == 0) {
#pragma unroll
        for (int j = 0; j < 8; ++j) {
            sh[wave][q * 8 + j] = s1[j];
            sh[wave][128 + q * 8 + j] = s2[j];
        }
    }
    __syncthreads();
    if (tid < 128) {
        float a = sh[0][tid] + sh[1][tid] + sh[2][tid] + sh[3][tid];
        float b = sh[0][128 + tid] + sh[1][128 + tid] + sh[2][128 + tid] + sh[3][128 + tid];
        atomicAdd(&colsum[tid], a);
        atomicAdd(&colsq[tid], b);
    }
}

// ---------------- BN finalize (separate 1-block kernel; self-zeroes stats) ----------------
__global__ void bn_fin(float* __restrict__ colsum, float* __restrict__ colsq,
                       const unsigned short* __restrict__ g, const unsigned short* __restrict__ beta,
                       const int* __restrict__ flag,
                       float* __restrict__ scale, float* __restrict__ shift, float invn) {
    int f = threadIdx.x;
    if (f >= 128) return;
    float cs = colsum[f], cq = colsq[f];
    colsum[f] = 0.f; colsq[f] = 0.f;
    if (!finitef(cs) || !finitef(cq)) { scale[f] = 0.f; shift[f] = 150.f; return; }
    float gv, bv;
    if (flag[0]) { gv = b2f(g[f]);            bv = b2f(beta[f]); }
    else         { gv = ((const float*)g)[f]; bv = ((const float*)beta)[f]; }
    float mu = cs * invn;
    float var = cq * invn - mu * mu;
    var = var < 0.f ? 0.f : var;
    float rstd = rsqrtf(var + 1e-5f);
    float s = gv * rstd;
    scale[f] = s;
    shift[f] = bv - mu * s;
}

// ---------------- final BN+ReLU to fp32 d_out, 8 elems/thread ----------------
__global__ void bn_apply_f32(const unsigned short* __restrict__ AGG, const float* __restrict__ scale,
                             const float* __restrict__ shift, float* __restrict__ out, int nchunk) {
    int i = blockIdx.x * 256 + threadIdx.x;
    if (i >= nchunk) return;
    int base = i * 8;
    int f0 = base & 127;
    uint4 hv = *(const uint4*)&AGG[base];
    unsigned short hu[8]; *(uint4*)hu = hv;
    float o[8];
#pragma unroll
    for (int j = 0; j < 8; ++j) {
        float v = b2f(hu[j]) * scale[f0 + j] + shift[f0 + j];
        o[j] = v > 0.f ? v : 0.f;
    }
    *(float4*)&out[base] = *(float4*)&o[0];
    *(float4*)&out[base + 4] = *(float4*)&o[4];
}

// ---------------- launch ----------------
extern "C" void kernel_launch(void* const* d_in, const int* in_sizes, int n_in,
                              void* d_out, int out_size, void* d_ws, size_t ws_size,
                              hipStream_t stream) {
    const unsigned short* X0 = (const unsigned short*)d_in[0];
    const int* ei = (const int*)d_in[1];
    const unsigned short* W1 = (const unsigned short*)d_in[2];
    const unsigned short* W2 = (const unsigned short*)d_in[4];
    const unsigned short* g1 = (const unsigned short*)d_in[6];
    const unsigned short* be1 = (const unsigned short*)d_in[7];
    const unsigned short* g2 = (const unsigned short*)d_in[8];
    const unsigned short* be2 = (const unsigned short*)d_in[9];
    float* OUT = (float*)d_out;

    int N = in_sizes[0] / HDIM;
    int E = in_sizes[1] / 2;
    int total = N * HDIM;
    int applyb = (total + 255) / 256;

    bool ok = (n_in == 10) && (N > 0) && (in_sizes[0] == N * HDIM) && (E > 0)
           && (in_sizes[2] == HDIM * HDIM) && (in_sizes[4] == HDIM * HDIM)
           && (in_sizes[6] == HDIM) && (in_sizes[9] == HDIM) && (out_size == total)
           && (N <= 65536);
    if (!ok) { fill_f32<<<applyb, 256, 0, stream>>>(OUT, total, -100.0f); return; }

    size_t need = (size_t)N * 28 + 2048 + 64 + 16 + 1024 + (size_t)E * 4
                + (size_t)total * 4 + 65536 + 512;
    if (ws_size < need) { fill_f32<<<applyb, 256, 0, stream>>>(OUT, total, -300.0f); return; }

    char* w = (char*)d_ws;
    int* cnt = (int*)w;       w += (size_t)N * 4;       // [zero region: cnt|stats]
    float* stats = (float*)w; w += 2048;                // colsum|colsq|scale|shift
    int* flags = (int*)w;     w += 16;                  // written by prep
    int* bsum = (int*)w;      w += 1024;
    float* dinv = (float*)w;  w += (size_t)N * 4;
    int* cursor = (int*)w;    w += (size_t)N * 4;
    w = (char*)(((uintptr_t)w + 15) & ~(uintptr_t)15);
    int4* meta = (int4*)w;    w += (size_t)N * 16;
    int* csr = (int*)w;       w += (size_t)E * 4;
    w = (char*)(((uintptr_t)w + 255) & ~(uintptr_t)255);
    unsigned short* Hb = (unsigned short*)w;  w += (size_t)total * 2;
    unsigned short* AGG = (unsigned short*)w; w += (size_t)total * 2;
    unsigned short* Wt1 = (unsigned short*)w; w += (size_t)HDIM * HDIM * 2;
    unsigned short* Wt2 = (unsigned short*)w; w += (size_t)HDIM * HDIM * 2;

    float* colsum = stats;
    float* colsq = stats + 128;
    float* scale = stats + 256;
    float* shift = stats + 384;

    int nb = (N + 255) / 256;
    int ebl = (E + 255) / 256;
    int gemmb = (N + 63) / 64;
    float invn = 1.0f / (float)N;
    int zcount = N + 512;

    prep<<<128 + (zcount + 255) / 256, 256, 0, stream>>>(X0, W1, W2, Wt1, Wt2, cnt, zcount, flags);
    edges_norm<<<ebl, 256, 0, stream>>>(ei, cnt, E, N);
    scan1<<<nb, 256, 0, stream>>>(cnt, bsum, dinv, N);
    scan3<<<nb, 256, 0, stream>>>(cnt, bsum, meta, cursor, N, nb);
    scatter_k<<<ebl, 256, 0, stream>>>(ei, cursor, csr, E, N);

    // layer 1
    gemm_mfma<<<gemmb, 256, 0, stream>>>(X0, Wt1, Hb, flags, -1, scale, shift, dinv, N);
    agg_stats<<<2048, 256, 0, stream>>>(Hb, meta, csr, AGG, colsum, colsq, N);
    bn_fin<<<1, 256, 0, stream>>>(colsum, colsq, g1, be1, flags, scale, shift, invn);

    // layer 2 (BN+ReLU fused into gemm A-staging)
    gemm_mfma<<<gemmb, 256, 0, stream>>>(AGG, Wt2, Hb, flags, 2, scale, shift, dinv, N);
    agg_stats<<<2048, 256, 0, stream>>>(Hb, meta, csr, AGG, colsum, colsq, N);
    bn_fin<<<1, 256, 0, stream>>>(colsum, colsq, g2, be2, flags, scale, shift, invn);
    bn_apply_f32<<<(total / 8 + 255) / 256, 256, 0, stream>>>(AGG, scale, shift, OUT, total / 8);
}